// Round 18
// baseline (42.017 us; speedup 1.0000x reference)
//
#include <hip/hip_runtime.h>

#define DIM     400
#define NENT    14541
#define B       32
#define NCAND   14505
#define NROUND  3627      // candidate quads
#define THREADS 256
#define DROWS   14508     // 4*NROUND rows in dense table
#define CVTN    (DROWS * 50)                       // 725400 uint4
#define CVTBLK  ((CVTN + THREADS - 1) / THREADS)   // 2834

typedef __attribute__((ext_vector_type(2))) _Float16 half2_t;

static __device__ __forceinline__ half2_t bch(unsigned u) {
    return __builtin_bit_cast(half2_t, u);
}
static __device__ __forceinline__ half2_t habs2(half2_t x) {
    unsigned u = __builtin_bit_cast(unsigned, x) & 0x7fff7fffu;
    return __builtin_bit_cast(half2_t, u);
}
static __device__ __forceinline__ unsigned pkh(float x, float y) {
    half2_t h;
    h.x = (_Float16)x;
    h.y = (_Float16)y;
    return __builtin_bit_cast(unsigned, h);
}
static __device__ __forceinline__ float dot2acc(half2_t m, float s) {
#if __has_builtin(__builtin_amdgcn_fdot2)
    const half2_t ones = {(_Float16)1.f, (_Float16)1.f};
    return __builtin_amdgcn_fdot2(m, ones, s, false);
#else
    return s + (float)m.x + (float)m.y;
#endif
}

// ---- setup: dense16[n] = f16(ent[cidx[n]]) — gather ONCE; score streams sequentially ----
__global__ void setup_kernel(const float* __restrict__ ent,
                             const int*   __restrict__ cidx,
                             uint4* __restrict__ dense16) {
    int i = blockIdx.x * THREADS + threadIdx.x;   // uint4 index: row*50 + col
    if (i >= CVTN) return;
    int row = i / 50;
    int col = i - row * 50;
    int n  = row < NCAND ? row : NCAND - 1;       // pad rows dup last cand
    int ci = cidx[n];
    const float4* s4 = (const float4*)(ent + (size_t)ci * DIM) + col * 2;
    float4 a = s4[0], c = s4[1];
    uint4 d;
    d.x = pkh(a.x, a.y);
    d.y = pkh(a.z, a.w);
    d.z = pkh(c.x, c.y);
    d.w = pkh(c.z, c.w);
    dense16[i] = d;
}

// ---- main: 1 batch/wave, 2 quad-streams over the DENSE f16 table; q/o prepped inline.
// wave = 4 cand-slots x 16 dim-lanes; lane u owns uint4-cols {u,u+16,u+32} + tail 48+u (u<2).
// Strip owns a contiguous 14-15-round range; all 8 bq-blocks of a strip share one XCD.
// Regs ~90 (q/o 32 + streams 32 + misc) << 128 budget -> zero spill; 8192 waves.
__global__ __launch_bounds__(THREADS, 2)
void score_f16(const uint4* __restrict__ dense16,
               const float* __restrict__ ent,
               const float* __restrict__ relc,
               const float* __restrict__ relo,
               const float* __restrict__ onev,
               const int*   __restrict__ pairs,
               float* __restrict__ out) {
    const int fid  = blockIdx.x;
    const int xcd  = fid & 7;
    const int rest = fid >> 3;
    const int bq   = rest & 7;           // 4-batch group
    const int tc   = rest >> 3;          // 0..31
    const int strip = xcd + 8 * tc;      // 0..255; 8 bq-blocks share this XCD

    // balanced contiguous range: strips 0..42 get 15 rounds, rest 14
    const int r0 = strip * 14 + (strip < 43 ? strip : 43);
    const int r1 = r0 + 14 + (strip < 43 ? 1 : 0);

    const int tid  = threadIdx.x;
    const int wid  = tid >> 6;
    const int lane = tid & 63;
    const int u    = lane & 15;
    const int g    = lane >> 4;
    const int b    = __builtin_amdgcn_readfirstlane(4 * bq + wid);

    // ---- inline q/o prep: load f32 h/rc/ro for this lane's dims, pack to f16 ----
    const int hd = pairs[2 * b + 0];
    const int rl = pairs[2 * b + 1];
    const float4* hp = (const float4*)(ent  + (size_t)hd * DIM);
    const float4* cp = (const float4*)(relc + (size_t)rl * DIM);
    const float4* op = (const float4*)(relo + (size_t)rl * DIM);

    uint4 q[4], o[4];
    float oa = 0.f;
#pragma unroll
    for (int k = 0; k < 3; ++k) {
        const int f = 2 * u + 32 * k;            // f4 chunk pair (f, f+1) = dims of col u+16k
        float4 h0 = hp[f], h1 = hp[f + 1];
        float4 c0 = cp[f], c1 = cp[f + 1];
        float4 v0 = op[f], v1 = op[f + 1];
        q[k].x = pkh(h0.x + c0.x, h0.y + c0.y);
        q[k].y = pkh(h0.z + c0.z, h0.w + c0.w);
        q[k].z = pkh(h1.x + c1.x, h1.y + c1.y);
        q[k].w = pkh(h1.z + c1.z, h1.w + c1.w);
        o[k].x = pkh(0.98f * v0.x, 0.98f * v0.y);
        o[k].y = pkh(0.98f * v0.z, 0.98f * v0.w);
        o[k].z = pkh(0.98f * v1.x, 0.98f * v1.y);
        o[k].w = pkh(0.98f * v1.z, 0.98f * v1.w);
        oa += v0.x + v0.y + v0.z + v0.w + v1.x + v1.y + v1.z + v1.w;
    }
    q[3] = q[0]; o[3] = o[0];
    if (u < 2) {
        const int f = 96 + 2 * u;                // tail col 48+u
        float4 h0 = hp[f], h1 = hp[f + 1];
        float4 c0 = cp[f], c1 = cp[f + 1];
        float4 v0 = op[f], v1 = op[f + 1];
        q[3].x = pkh(h0.x + c0.x, h0.y + c0.y);
        q[3].y = pkh(h0.z + c0.z, h0.w + c0.w);
        q[3].z = pkh(h1.x + c1.x, h1.y + c1.y);
        q[3].w = pkh(h1.z + c1.z, h1.w + c1.w);
        o[3].x = pkh(0.98f * v0.x, 0.98f * v0.y);
        o[3].y = pkh(0.98f * v0.z, 0.98f * v0.w);
        o[3].z = pkh(0.98f * v1.x, 0.98f * v1.y);
        o[3].w = pkh(0.98f * v1.z, 0.98f * v1.w);
        oa += v0.x + v0.y + v0.z + v0.w + v1.x + v1.y + v1.z + v1.w;
    }
    oa += __shfl_xor(oa, 1);
    oa += __shfl_xor(oa, 2);
    oa += __shfl_xor(oa, 4);
    oa += __shfl_xor(oa, 8);                     // full 400-dim sum (16 dim-lanes)
    const float base = onev[0] + 0.98f * oa;

    const half2_t K002 = {(_Float16)0.02f, (_Float16)0.02f};

#define PAIR(cu, qu, ou, SS)                                    \
    {                                                           \
        half2_t cc_ = bch(cu), qq_ = bch(qu), oo_ = bch(ou);    \
        half2_t dd_ = cc_ - qq_;                                \
        half2_t aa_ = habs2(dd_);                               \
        half2_t ee_ = aa_ * K002 + oo_;                         \
        half2_t mm_ = __builtin_elementwise_max(aa_, ee_);      \
        SS = dot2acc(mm_, SS);                                  \
    }
#define PROC(C, Q, O, SA, SB)                                   \
    PAIR(C.x, Q.x, O.x, SA) PAIR(C.y, Q.y, O.y, SB)             \
    PAIR(C.z, Q.z, O.z, SA) PAIR(C.w, Q.w, O.w, SB)

    for (int rr = r0; rr < r1; rr += 2) {
        const int rA = rr;
        const int rB = (rr + 1 < r1) ? rr + 1 : rr;   // odd tail: dup A, skip B store
        const uint4* pA = dense16 + (size_t)(4 * rA + g) * 50;
        const uint4* pB = dense16 + (size_t)(4 * rB + g) * 50;

        uint4 av0 = pA[u], av1 = pA[u + 16], av2 = pA[u + 32];
        uint4 bv0 = pB[u], bv1 = pB[u + 16], bv2 = pB[u + 32];
        uint4 av3, bv3;
        if (u < 2) { av3 = pA[48 + u]; bv3 = pB[48 + u]; }

        float sA0 = 0.f, sA1 = 0.f, sB0 = 0.f, sB1 = 0.f;
        PROC(av0, q[0], o[0], sA0, sA1)
        PROC(av1, q[1], o[1], sA0, sA1)
        PROC(av2, q[2], o[2], sA0, sA1)
        if (u < 2) { PROC(av3, q[3], o[3], sA0, sA1) }
        PROC(bv0, q[0], o[0], sB0, sB1)
        PROC(bv1, q[1], o[1], sB0, sB1)
        PROC(bv2, q[2], o[2], sB0, sB1)
        if (u < 2) { PROC(bv3, q[3], o[3], sB0, sB1) }

        float sA = sA0 + sA1;
        float sB = sB0 + sB1;
        sA += __shfl_xor(sA, 1); sB += __shfl_xor(sB, 1);
        sA += __shfl_xor(sA, 2); sB += __shfl_xor(sB, 2);
        sA += __shfl_xor(sA, 4); sB += __shfl_xor(sB, 4);
        sA += __shfl_xor(sA, 8); sB += __shfl_xor(sB, 8);

        if (u == 0) {
            const int candA = 4 * rA + g;
            const int candB = 4 * rB + g;
            if (candA < NCAND)
                out[(size_t)b * NCAND + candA] = base - sA;
            if (rB != rA && candB < NCAND)
                out[(size_t)b * NCAND + candB] = base - sB;
        }
    }
#undef PROC
#undef PAIR
}

// ---- fallback (no ws): R9 f32 kernel verbatim ----
__global__ __launch_bounds__(THREADS, 2)
void score_f32(const float* __restrict__ ent,
               const float* __restrict__ relc,
               const float* __restrict__ relo,
               const float* __restrict__ onev,
               const int*   __restrict__ pairs,
               const int*   __restrict__ cidx,
               float* __restrict__ out) {
    const int fid  = blockIdx.x;
    const int xcd  = fid & 7;
    const int rest = fid >> 3;
    const int bq   = rest & 7;
    const int tc   = rest >> 3;
    const int t    = xcd + 8 * tc;

    const int tid  = threadIdx.x;
    const int lane = tid & 63;
    const int u    = lane & 15;
    const int g    = lane >> 4;
    const int b    = __builtin_amdgcn_readfirstlane(bq * 4 + (tid >> 6));

    const int hd = pairs[b * 2 + 0];
    const int rl = pairs[b * 2 + 1];
    const float4* hb = (const float4*)(ent  + (size_t)hd * DIM) + u;
    const float4* cb = (const float4*)(relc + (size_t)rl * DIM) + u;
    const float4* ob = (const float4*)(relo + (size_t)rl * DIM) + u;

    float4 q[7], o[7];
    float oa = 0.f;
#pragma unroll
    for (int k = 0; k < 6; ++k) {
        float4 h = hb[16 * k], c = cb[16 * k];
        q[k] = make_float4(h.x + c.x, h.y + c.y, h.z + c.z, h.w + c.w);
        o[k] = ob[16 * k];
        oa += o[k].x + o[k].y + o[k].z + o[k].w;
    }
    if (u < 4) {
        float4 h = hb[96], c = cb[96];
        q[6] = make_float4(h.x + c.x, h.y + c.y, h.z + c.z, h.w + c.w);
        o[6] = ob[96];
        oa += o[6].x + o[6].y + o[6].z + o[6].w;
    }
    oa += __shfl_xor(oa, 1);
    oa += __shfl_xor(oa, 2);
    oa += __shfl_xor(oa, 4);
    oa += __shfl_xor(oa, 8);
    const float base = onev[0] + 0.98f * oa;

    const float4* entu = (const float4*)ent + u;

#define E(vc, vq, vo, AM, AD)                     \
        {                                         \
            float d_ = (vc) - (vq);               \
            AM += fmaxf(fabsf(d_), (vo));         \
            AD += fabsf(d_);                      \
        }
#define F4(k, AM, AD)                             \
        E(cbuf[k].x, q[k].x, o[k].x, AM, AD)      \
        E(cbuf[k].y, q[k].y, o[k].y, AM, AD)      \
        E(cbuf[k].z, q[k].z, o[k].z, AM, AD)      \
        E(cbuf[k].w, q[k].w, o[k].w, AM, AD)

    for (int rr = t; rr < NROUND; rr += 256) {
        const int cand = 4 * rr + g;
        const int ci   = cidx[cand < NCAND ? cand : NCAND - 1];
        const float4* p = entu + (size_t)ci * 100;

        float4 cbuf[7];
#pragma unroll
        for (int k = 0; k < 6; ++k) cbuf[k] = p[16 * k];
        if (u < 4) cbuf[6] = p[96];

        float am0 = 0.f, ad0 = 0.f, am1 = 0.f, ad1 = 0.f;
        F4(0, am0, ad0) F4(1, am1, ad1)
        F4(2, am0, ad0) F4(3, am1, ad1)
        F4(4, am0, ad0) F4(5, am1, ad1)
        if (u < 4) { F4(6, am0, ad0) }

        float s_ = fmaf(-0.98f, am0 + am1, -0.02f * (ad0 + ad1));
        s_ += __shfl_xor(s_, 1);
        s_ += __shfl_xor(s_, 2);
        s_ += __shfl_xor(s_, 4);
        s_ += __shfl_xor(s_, 8);

        if (u == 0 && cand < NCAND)
            out[(size_t)b * NCAND + cand] = base + s_;
    }
#undef F4
#undef E
}

extern "C" void kernel_launch(void* const* d_in, const int* in_sizes, int n_in,
                              void* d_out, int out_size, void* d_ws, size_t ws_size,
                              hipStream_t stream) {
    const float* ent   = (const float*)d_in[0];
    const float* relc  = (const float*)d_in[1];
    const float* relo  = (const float*)d_in[2];
    const float* onev  = (const float*)d_in[3];
    const int*   pairs = (const int*)d_in[4];
    const int*   cidx  = (const int*)d_in[5];
    float*       out   = (float*)d_out;

    const size_t denB = (size_t)DROWS * DIM * 2;     // 11,606,400 B

    if (ws_size >= denB) {
        uint4* dense16 = (uint4*)d_ws;
        setup_kernel<<<CVTBLK, THREADS, 0, stream>>>(ent, cidx, dense16);
        score_f16<<<8 * 8 * 32, THREADS, 0, stream>>>(   // 2048 blocks, 8192 waves
            dense16, ent, relc, relo, onev, pairs, out);
    } else {
        score_f32<<<8 * 8 * 32, THREADS, 0, stream>>>(
            ent, relc, relo, onev, pairs, cidx, out);
    }
}